// Round 2
// baseline (7170.650 us; speedup 1.0000x reference)
//
#include <hip/hip_runtime.h>
#include <math.h>

#define NND 20000
#define NE  320000
#define NF  128
#define K1P 288            // DIN=262 zero-padded to 288 (9 slabs of 32)
#define EPS 1e-5f
#define TE  64             // edges per tile
#define NT  256
#define NTILES (NE / TE)   // 5000
#define XST 136            // LDS stride for 128-wide bf16 tiles (shorts)
#define BST 40             // LDS stride for B slab rows (shorts)

typedef short short8 __attribute__((ext_vector_type(8)));
typedef float float4v __attribute__((ext_vector_type(4)));

__device__ __forceinline__ float psif(float z) {
    return copysignf(log1pf(fabsf(z)), z);
}
__device__ __forceinline__ float sigm(float z) {
    return 1.f / (1.f + expf(-z));
}
__device__ __forceinline__ short f2bf(float f) {
    union { float f; unsigned u; } v; v.f = f;
    unsigned r = v.u + 0x7fffu + ((v.u >> 16) & 1u);
    return (short)(r >> 16);
}
__device__ __forceinline__ float clipf(float v) {
    return fminf(fmaxf(v, -100.f), 100.f);
}

// stage one K=32 slab of Wt [128 rows n][wstride k] (bf16/ushort) into LDS bt[128][BST]
__device__ __forceinline__ void stage_b(const unsigned short* __restrict__ wsrc, int wstride,
                                        int ks, short* bt, int t) {
    #pragma unroll
    for (int rr = 0; rr < 2; ++rr) {
        int c = t + rr * 256;          // 512 chunks of 8 bf16
        int n = c >> 2, h = c & 3;
        short8 v = *(const short8*)(wsrc + (size_t)n * wstride + ks * 32 + h * 8);
        *(short8*)(bt + n * BST + h * 8) = v;
    }
}

// gather 64-edge tile: fp32 x rows -> bf16 LDS tiles + psi(norm), psi(dot), eattr -> ext
__device__ __forceinline__ void gather_tile(const float* __restrict__ x,
                                            const int* __restrict__ ridx,
                                            const int* __restrict__ cidx,
                                            const float* __restrict__ eattr,
                                            int e0, int t,
                                            short* lxi, short* lxj, short* lext) {
    const int le = t >> 2, q = t & 3;
    const int r = ridx[le], c = cidx[le];
    const float4* xr4 = (const float4*)(x + (size_t)r * NF) + q * 8;
    const float4* xc4 = (const float4*)(x + (size_t)c * NF) + q * 8;
    float nrm = 0.f, dot = 0.f, a00 = 0.f, b00 = 0.f;
    #pragma unroll
    for (int u = 0; u < 4; ++u) {
        float4 a0 = xr4[2*u], a1 = xr4[2*u+1];
        float4 b0 = xc4[2*u], b1 = xc4[2*u+1];
        if (u == 0) { a00 = a0.x; b00 = b0.x; }
        float d;
        d = a0.x-b0.x; nrm -= d*d; dot -= a0.x*b0.x;
        d = a0.y-b0.y; nrm -= d*d; dot -= a0.y*b0.y;
        d = a0.z-b0.z; nrm -= d*d; dot -= a0.z*b0.z;
        d = a0.w-b0.w; nrm -= d*d; dot -= a0.w*b0.w;
        d = a1.x-b1.x; nrm -= d*d; dot -= a1.x*b1.x;
        d = a1.y-b1.y; nrm -= d*d; dot -= a1.y*b1.y;
        d = a1.z-b1.z; nrm -= d*d; dot -= a1.z*b1.z;
        d = a1.w-b1.w; nrm -= d*d; dot -= a1.w*b1.w;
        short8 sa, sb;
        sa[0]=f2bf(a0.x); sa[1]=f2bf(a0.y); sa[2]=f2bf(a0.z); sa[3]=f2bf(a0.w);
        sa[4]=f2bf(a1.x); sa[5]=f2bf(a1.y); sa[6]=f2bf(a1.z); sa[7]=f2bf(a1.w);
        sb[0]=f2bf(b0.x); sb[1]=f2bf(b0.y); sb[2]=f2bf(b0.z); sb[3]=f2bf(b0.w);
        sb[4]=f2bf(b1.x); sb[5]=f2bf(b1.y); sb[6]=f2bf(b1.z); sb[7]=f2bf(b1.w);
        *(short8*)(lxi + le * XST + q * 32 + u * 8) = sa;
        *(short8*)(lxj + le * XST + q * 32 + u * 8) = sb;
    }
    if (q == 0) {  // metric fix: component 0 carries +, not -
        float d0 = a00 - b00;
        nrm += 2.f * d0 * d0;
        dot += 2.f * a00 * b00;
    }
    nrm += __shfl_xor(nrm, 1); nrm += __shfl_xor(nrm, 2);
    dot += __shfl_xor(dot, 1); dot += __shfl_xor(dot, 2);
    if (q == 0) {
        float4 ea = ((const float4*)eattr)[e0 + le];
        short8 ev;
        ev[0]=f2bf(ea.x); ev[1]=f2bf(ea.y); ev[2]=f2bf(ea.z); ev[3]=f2bf(ea.w);
        ev[4]=f2bf(psif(nrm)); ev[5]=f2bf(psif(dot)); ev[6]=0; ev[7]=0;
        *(short8*)(lext + le * 32) = ev;
    } else {
        short8 ez = {0,0,0,0,0,0,0,0};
        *(short8*)(lext + le * 32 + q * 8) = ez;
    }
}

// ---------------------------------------------------------------------------
// Pass 1: MFMA GEMM0 -> per-channel sum/sumsq (register accumulation)
// ---------------------------------------------------------------------------
__global__ __launch_bounds__(NT, 3)
void stats_pass(const float* __restrict__ x,
                const int* __restrict__ ei,
                const float* __restrict__ eattr,
                const unsigned short* __restrict__ wt1,
                float* __restrict__ gstats)
{
    __shared__ short lxi[TE * XST];
    __shared__ short lxj[TE * XST];
    __shared__ short lext[TE * 32];
    __shared__ short lbt[128 * BST];
    __shared__ int ridx[TE], cidx[TE];

    const int t = threadIdx.x;
    const int lane = t & 63, quad = lane >> 4, ln15 = lane & 15;
    const int wv = t >> 6, we = wv >> 1, wc = wv & 1;

    float ss[4] = {0.f,0.f,0.f,0.f}, sq[4] = {0.f,0.f,0.f,0.f};

    for (int tile = blockIdx.x; tile < NTILES; tile += gridDim.x) {
        const int e0 = tile * TE;
        __syncthreads();
        if (t < TE) ridx[t] = ei[e0 + t];
        else if (t < 2 * TE) cidx[t - TE] = ei[NE + e0 + (t - TE)];
        __syncthreads();
        gather_tile(x, ridx, cidx, eattr, e0, t, lxi, lxj, lext);

        float4v acc[2][4];
        #pragma unroll
        for (int a = 0; a < 2; ++a)
            #pragma unroll
            for (int b = 0; b < 4; ++b) { float4v z = {0.f,0.f,0.f,0.f}; acc[a][b] = z; }

        for (int ks = 0; ks < 9; ++ks) {
            __syncthreads();
            stage_b(wt1, K1P, ks, lbt, t);
            __syncthreads();
            const short* asrc; int ak, astr;
            if (ks < 4)      { asrc = lxi;  ak = ks * 32;       astr = XST; }
            else if (ks < 8) { asrc = lxj;  ak = (ks - 4) * 32; astr = XST; }
            else             { asrc = lext; ak = 0;             astr = 32;  }
            short8 af[2], bfr[4];
            #pragma unroll
            for (int ef = 0; ef < 2; ++ef)
                af[ef] = *(const short8*)(asrc + (we*32 + ef*16 + ln15) * astr + ak + quad*8);
            #pragma unroll
            for (int fc = 0; fc < 4; ++fc)
                bfr[fc] = *(const short8*)(lbt + (wc*64 + fc*16 + ln15) * BST + quad*8);
            #pragma unroll
            for (int ef = 0; ef < 2; ++ef)
                #pragma unroll
                for (int fc = 0; fc < 4; ++fc)
                    acc[ef][fc] = __builtin_amdgcn_mfma_f32_16x16x32_bf16(af[ef], bfr[fc], acc[ef][fc], 0, 0, 0);
        }
        #pragma unroll
        for (int fc = 0; fc < 4; ++fc)
            #pragma unroll
            for (int ef = 0; ef < 2; ++ef)
                #pragma unroll
                for (int rg = 0; rg < 4; ++rg) {
                    float v = acc[ef][fc][rg];
                    ss[fc] += v;
                    sq[fc] = fmaf(v, v, sq[fc]);
                }
    }
    #pragma unroll
    for (int fc = 0; fc < 4; ++fc) {
        ss[fc] += __shfl_xor(ss[fc], 16); ss[fc] += __shfl_xor(ss[fc], 32);
        sq[fc] += __shfl_xor(sq[fc], 16); sq[fc] += __shfl_xor(sq[fc], 32);
    }
    if (lane < 16) {
        #pragma unroll
        for (int fc = 0; fc < 4; ++fc) {
            int c = wc * 64 + fc * 16 + lane;
            atomicAdd(&gstats[c], ss[fc]);
            atomicAdd(&gstats[128 + c], sq[fc]);
        }
    }
}

// ---------------------------------------------------------------------------
__global__ void bn_finalize(const float* __restrict__ gstats,
                            const float* __restrict__ gamma,
                            const float* __restrict__ beta,
                            float* __restrict__ scsh)
{
    int c = threadIdx.x;
    float mu  = gstats[c] * (1.f / NE);
    float var = gstats[128 + c] * (1.f / NE) - mu * mu;
    var = fmaxf(var, 0.f);
    float inv = rsqrtf(var + EPS);
    float scale = gamma[c] * inv;
    scsh[c]       = scale;
    scsh[128 + c] = beta[c] - mu * scale;
}

// ---------------------------------------------------------------------------
// Pass 2: GEMM0->BN->ReLU->GEMM1->gate->GEMM2->Wb dot->scatter
// ---------------------------------------------------------------------------
__global__ __launch_bounds__(NT, 3)
void edge_pass(const float* __restrict__ x,
               float* __restrict__ xn,
               const int* __restrict__ ei,
               const float* __restrict__ eattr,
               const unsigned short* __restrict__ wt1,
               const float* __restrict__ scsh,
               const unsigned short* __restrict__ wt2,
               const float* __restrict__ b2,
               const unsigned short* __restrict__ wta,
               const float* __restrict__ ba,
               const float* __restrict__ wb,
               const float* __restrict__ wm,
               const float* __restrict__ bm)
{
    __shared__ short lxi[TE * XST];
    __shared__ short lxj[TE * XST];
    __shared__ short lext[TE * 32];
    __shared__ short lbt[128 * BST];
    __shared__ int ridx[TE], cidx[TE];
    __shared__ float gpart[2][TE];
    __shared__ float spart[2][TE];
    __shared__ float wgt[TE];
    __shared__ float sval[TE];

    const int t = threadIdx.x;
    const int lane = t & 63, quad = lane >> 4, ln15 = lane & 15;
    const int wv = t >> 6, we = wv >> 1, wc = wv & 1;
    const int e0 = blockIdx.x * TE;
    const float bmv = bm[0];

    if (t < TE) ridx[t] = ei[e0 + t];
    else if (t < 2 * TE) cidx[t - TE] = ei[NE + e0 + (t - TE)];
    __syncthreads();
    gather_tile(x, ridx, cidx, eattr, e0, t, lxi, lxj, lext);

    float4v acc[2][4];
    #pragma unroll
    for (int a = 0; a < 2; ++a)
        #pragma unroll
        for (int b = 0; b < 4; ++b) { float4v z = {0.f,0.f,0.f,0.f}; acc[a][b] = z; }

    // ---- GEMM0: hpre = m @ W1 ----
    for (int ks = 0; ks < 9; ++ks) {
        __syncthreads();
        stage_b(wt1, K1P, ks, lbt, t);
        __syncthreads();
        const short* asrc; int ak, astr;
        if (ks < 4)      { asrc = lxi;  ak = ks * 32;       astr = XST; }
        else if (ks < 8) { asrc = lxj;  ak = (ks - 4) * 32; astr = XST; }
        else             { asrc = lext; ak = 0;             astr = 32;  }
        short8 af[2], bfr[4];
        #pragma unroll
        for (int ef = 0; ef < 2; ++ef)
            af[ef] = *(const short8*)(asrc + (we*32 + ef*16 + ln15) * astr + ak + quad*8);
        #pragma unroll
        for (int fc = 0; fc < 4; ++fc)
            bfr[fc] = *(const short8*)(lbt + (wc*64 + fc*16 + ln15) * BST + quad*8);
        #pragma unroll
        for (int ef = 0; ef < 2; ++ef)
            #pragma unroll
            for (int fc = 0; fc < 4; ++fc)
                acc[ef][fc] = __builtin_amdgcn_mfma_f32_16x16x32_bf16(af[ef], bfr[fc], acc[ef][fc], 0, 0, 0);
    }

    // epilogue0: BN + ReLU -> hid (bf16) into lxi   (lxi reads finished: slab<=3)
    #pragma unroll
    for (int fc = 0; fc < 4; ++fc) {
        int c = wc * 64 + fc * 16 + ln15;
        float sc = scsh[c], sf = scsh[128 + c];
        #pragma unroll
        for (int ef = 0; ef < 2; ++ef)
            #pragma unroll
            for (int rg = 0; rg < 4; ++rg) {
                int r = we * 32 + ef * 16 + quad * 4 + rg;
                float v = fmaxf(fmaf(acc[ef][fc][rg], sc, sf), 0.f);
                lxi[r * XST + c] = f2bf(v);
            }
    }

    // ---- GEMM1: mij_raw = relu(hid @ W2 + b2) ----
    #pragma unroll
    for (int a = 0; a < 2; ++a)
        #pragma unroll
        for (int b = 0; b < 4; ++b) { float4v z = {0.f,0.f,0.f,0.f}; acc[a][b] = z; }
    for (int ks = 0; ks < 4; ++ks) {
        __syncthreads();
        stage_b(wt2, NF, ks, lbt, t);
        __syncthreads();
        short8 af[2], bfr[4];
        #pragma unroll
        for (int ef = 0; ef < 2; ++ef)
            af[ef] = *(const short8*)(lxi + (we*32 + ef*16 + ln15) * XST + ks*32 + quad*8);
        #pragma unroll
        for (int fc = 0; fc < 4; ++fc)
            bfr[fc] = *(const short8*)(lbt + (wc*64 + fc*16 + ln15) * BST + quad*8);
        #pragma unroll
        for (int ef = 0; ef < 2; ++ef)
            #pragma unroll
            for (int fc = 0; fc < 4; ++fc)
                acc[ef][fc] = __builtin_amdgcn_mfma_f32_16x16x32_bf16(af[ef], bfr[fc], acc[ef][fc], 0, 0, 0);
    }

    // epilogue1: +b2, ReLU -> mij (bf16) into lxj; gate partial dots with Wm
    {
        float p[2][4] = {{0.f,0.f,0.f,0.f},{0.f,0.f,0.f,0.f}};
        #pragma unroll
        for (int fc = 0; fc < 4; ++fc) {
            int c = wc * 64 + fc * 16 + ln15;
            float bb = b2[c], wmv = wm[c];
            #pragma unroll
            for (int ef = 0; ef < 2; ++ef)
                #pragma unroll
                for (int rg = 0; rg < 4; ++rg) {
                    int r = we * 32 + ef * 16 + quad * 4 + rg;
                    float v = fmaxf(acc[ef][fc][rg] + bb, 0.f);
                    lxj[r * XST + c] = f2bf(v);
                    p[ef][rg] = fmaf(v, wmv, p[ef][rg]);
                }
        }
        #pragma unroll
        for (int ef = 0; ef < 2; ++ef)
            #pragma unroll
            for (int rg = 0; rg < 4; ++rg) {
                p[ef][rg] += __shfl_xor(p[ef][rg], 1);
                p[ef][rg] += __shfl_xor(p[ef][rg], 2);
                p[ef][rg] += __shfl_xor(p[ef][rg], 4);
                p[ef][rg] += __shfl_xor(p[ef][rg], 8);
            }
        if (ln15 == 0) {
            #pragma unroll
            for (int ef = 0; ef < 2; ++ef)
                #pragma unroll
                for (int rg = 0; rg < 4; ++rg)
                    gpart[wc][we * 32 + ef * 16 + quad * 4 + rg] = p[ef][rg];
        }
    }
    __syncthreads();
    if (t < TE) wgt[t] = sigm(gpart[0][t] + gpart[1][t] + bmv);

    // ---- GEMM2: relu(w * (mij_raw @ Wa) + ba) . Wb ----
    #pragma unroll
    for (int a = 0; a < 2; ++a)
        #pragma unroll
        for (int b = 0; b < 4; ++b) { float4v z = {0.f,0.f,0.f,0.f}; acc[a][b] = z; }
    for (int ks = 0; ks < 4; ++ks) {
        __syncthreads();
        stage_b(wta, NF, ks, lbt, t);
        __syncthreads();
        short8 af[2], bfr[4];
        #pragma unroll
        for (int ef = 0; ef < 2; ++ef)
            af[ef] = *(const short8*)(lxj + (we*32 + ef*16 + ln15) * XST + ks*32 + quad*8);
        #pragma unroll
        for (int fc = 0; fc < 4; ++fc)
            bfr[fc] = *(const short8*)(lbt + (wc*64 + fc*16 + ln15) * BST + quad*8);
        #pragma unroll
        for (int ef = 0; ef < 2; ++ef)
            #pragma unroll
            for (int fc = 0; fc < 4; ++fc)
                acc[ef][fc] = __builtin_amdgcn_mfma_f32_16x16x32_bf16(af[ef], bfr[fc], acc[ef][fc], 0, 0, 0);
    }
    {
        float p[2][4] = {{0.f,0.f,0.f,0.f},{0.f,0.f,0.f,0.f}};
        #pragma unroll
        for (int fc = 0; fc < 4; ++fc) {
            int c = wc * 64 + fc * 16 + ln15;
            float bav = ba[c], wbv = wb[c];
            #pragma unroll
            for (int ef = 0; ef < 2; ++ef)
                #pragma unroll
                for (int rg = 0; rg < 4; ++rg) {
                    int r = we * 32 + ef * 16 + quad * 4 + rg;
                    float v = fmaxf(fmaf(wgt[r], acc[ef][fc][rg], bav), 0.f);
                    p[ef][rg] = fmaf(v, wbv, p[ef][rg]);
                }
        }
        #pragma unroll
        for (int ef = 0; ef < 2; ++ef)
            #pragma unroll
            for (int rg = 0; rg < 4; ++rg) {
                p[ef][rg] += __shfl_xor(p[ef][rg], 1);
                p[ef][rg] += __shfl_xor(p[ef][rg], 2);
                p[ef][rg] += __shfl_xor(p[ef][rg], 4);
                p[ef][rg] += __shfl_xor(p[ef][rg], 8);
            }
        if (ln15 == 0) {
            #pragma unroll
            for (int ef = 0; ef < 2; ++ef)
                #pragma unroll
                for (int rg = 0; rg < 4; ++rg)
                    spart[wc][we * 32 + ef * 16 + quad * 4 + rg] = p[ef][rg];
        }
    }
    __syncthreads();
    if (t < TE) sval[t] = spart[0][t] + spart[1][t];
    __syncthreads();

    // scatter: xn[row] += clip(x_diff * s)  (fp32 re-read of x, L2-hot)
    {
        const int le = t >> 2, q = t & 3;
        const float s = sval[le];
        const int r = ridx[le], c = cidx[le];
        const float4* xr4 = (const float4*)(x + (size_t)r * NF) + q * 8;
        const float4* xc4 = (const float4*)(x + (size_t)c * NF) + q * 8;
        float* dst = xn + (size_t)r * NF + q * 32;
        #pragma unroll
        for (int u = 0; u < 8; ++u) {
            float4 a = xr4[u], b = xc4[u];
            atomicAdd(dst + u * 4 + 0, clipf((a.x - b.x) * s));
            atomicAdd(dst + u * 4 + 1, clipf((a.y - b.y) * s));
            atomicAdd(dst + u * 4 + 2, clipf((a.z - b.z) * s));
            atomicAdd(dst + u * 4 + 3, clipf((a.w - b.w) * s));
        }
    }
}

// ---------------------------------------------------------------------------
__global__ __launch_bounds__(NT)
void copyk(const float* __restrict__ src, float* __restrict__ dst, int n4)
{
    int i = blockIdx.x * NT + threadIdx.x;
    if (i < n4) ((float4*)dst)[i] = ((const float4*)src)[i];
}

__global__ __launch_bounds__(NT)
void prep_w1(const float* __restrict__ W1, unsigned short* __restrict__ wt1)
{
    int i = blockIdx.x * NT + threadIdx.x;
    if (i >= 3 * 128 * K1P) return;
    int l = i / (128 * K1P);
    int r = i % (128 * K1P);
    int n = r / K1P, k = r % K1P;
    float v = (k < 262) ? W1[((size_t)l * 262 + k) * 128 + n] : 0.f;
    wt1[i] = (unsigned short)f2bf(v);
}

__global__ __launch_bounds__(NT)
void prep_w128(const float* __restrict__ W, unsigned short* __restrict__ wt)
{
    int i = blockIdx.x * NT + threadIdx.x;
    if (i >= 3 * 128 * 128) return;
    int l = i / (128 * 128);
    int r = i % (128 * 128);
    int n = r / 128, k = r % 128;
    wt[i] = (unsigned short)f2bf(W[((size_t)l * 128 + k) * 128 + n]);
}

__global__ __launch_bounds__(NT)
void finalk(const float* __restrict__ x, const float* __restrict__ We,
            const float* __restrict__ be, float* __restrict__ out)
{
    int gw = (blockIdx.x * NT + threadIdx.x) >> 6;
    int ln = threadIdx.x & 63;
    if (gw >= NND) return;
    const float* xr = x + (size_t)gw * NF;
    float a0 = xr[ln], a1 = xr[ln + 64];
    float o0 = a0 * We[ln * 2]     + a1 * We[(ln + 64) * 2];
    float o1 = a0 * We[ln * 2 + 1] + a1 * We[(ln + 64) * 2 + 1];
    #pragma unroll
    for (int m = 1; m < 64; m <<= 1) { o0 += __shfl_xor(o0, m); o1 += __shfl_xor(o1, m); }
    if (ln == 0) {
        out[gw * 2]     = sigm(o0 + be[0]);
        out[gw * 2 + 1] = sigm(o1 + be[1]);
    }
}

// ---------------------------------------------------------------------------
extern "C" void kernel_launch(void* const* d_in, const int* in_sizes, int n_in,
                              void* d_out, int out_size, void* d_ws, size_t ws_size,
                              hipStream_t stream) {
    const float* x   = (const float*)d_in[0];
    const int*   ei  = (const int*)d_in[1];
    const float* ea  = (const float*)d_in[2];
    const float* W1  = (const float*)d_in[3];
    const float* ga  = (const float*)d_in[4];
    const float* bet = (const float*)d_in[5];
    const float* W2  = (const float*)d_in[6];
    const float* b2  = (const float*)d_in[7];
    const float* Wa  = (const float*)d_in[8];
    const float* ba  = (const float*)d_in[9];
    const float* Wb  = (const float*)d_in[10];
    const float* Wm  = (const float*)d_in[11];
    const float* bm  = (const float*)d_in[12];
    const float* We  = (const float*)d_in[13];
    const float* be  = (const float*)d_in[14];
    float* out = (float*)d_out;

    float* ws     = (float*)d_ws;
    float* gstats = ws;                              // 256 f
    float* scsh   = ws + 256;                        // 256 f
    float* xA     = ws + 512;
    float* xB     = xA + (size_t)NND * NF;
    unsigned short* wt1 = (unsigned short*)(xB + (size_t)NND * NF);
    unsigned short* wt2 = wt1 + (size_t)3 * 128 * K1P;
    unsigned short* wta = wt2 + (size_t)3 * 128 * 128;

    prep_w1  <<<(3 * 128 * K1P + NT - 1) / NT, NT, 0, stream>>>(W1, wt1);
    prep_w128<<<(3 * 128 * 128 + NT - 1) / NT, NT, 0, stream>>>(W2, wt2);
    prep_w128<<<(3 * 128 * 128 + NT - 1) / NT, NT, 0, stream>>>(Wa, wta);

    const float* xc = x;
    float* buf[2] = { xA, xB };

    for (int l = 0; l < 3; ++l) {
        float* xn = buf[l & 1];
        hipMemsetAsync(gstats, 0, 256 * sizeof(float), stream);
        copyk<<<(NND * NF / 4 + NT - 1) / NT, NT, 0, stream>>>(xc, xn, NND * NF / 4);
        stats_pass<<<1024, NT, 0, stream>>>(xc, ei, ea, wt1 + (size_t)l * 128 * K1P, gstats);
        bn_finalize<<<1, 128, 0, stream>>>(gstats, ga + l * NF, bet + l * NF, scsh);
        edge_pass<<<NTILES, NT, 0, stream>>>(xc, xn, ei, ea,
                                             wt1 + (size_t)l * 128 * K1P, scsh,
                                             wt2 + (size_t)l * 128 * 128, b2 + l * NF,
                                             wta + (size_t)l * 128 * 128, ba + l * NF,
                                             Wb + l * NF, Wm + l * NF, bm + l);
        xc = xn;
    }
    finalk<<<(NND * 64 + NT - 1) / NT, NT, 0, stream>>>(xc, We, be, out);
}

// Round 3
// 1202.518 us; speedup vs baseline: 5.9630x; 5.9630x over previous
//
#include <hip/hip_runtime.h>
#include <math.h>

#define NND 20000
#define NE  320000
#define NF  128
#define K1P 288            // DIN=262 zero-padded to 288 (9 slabs of 32)
#define EPS 1e-5f
#define TE  64             // edges per tile
#define NT  256
#define NTILES (NE / TE)   // 5000
#define XST 136            // LDS stride for 128-wide bf16 tiles (shorts)
#define BST 40             // LDS stride for B slab rows (shorts)

typedef short short8 __attribute__((ext_vector_type(8)));
typedef float float4v __attribute__((ext_vector_type(4)));

__device__ __forceinline__ float psif(float z) {
    return copysignf(log1pf(fabsf(z)), z);
}
__device__ __forceinline__ float sigm(float z) {
    return 1.f / (1.f + expf(-z));
}
__device__ __forceinline__ short f2bf(float f) {
    union { float f; unsigned u; } v; v.f = f;
    unsigned r = v.u + 0x7fffu + ((v.u >> 16) & 1u);
    return (short)(r >> 16);
}
__device__ __forceinline__ float clipf(float v) {
    return fminf(fmaxf(v, -100.f), 100.f);
}

// stage one K=32 slab of Wt [128 rows n][wstride k] (bf16/ushort) into LDS bt[128][BST]
__device__ __forceinline__ void stage_b(const unsigned short* __restrict__ wsrc, int wstride,
                                        int ks, short* bt, int t) {
    #pragma unroll
    for (int rr = 0; rr < 2; ++rr) {
        int c = t + rr * 256;          // 512 chunks of 8 bf16
        int n = c >> 2, h = c & 3;
        short8 v = *(const short8*)(wsrc + (size_t)n * wstride + ks * 32 + h * 8);
        *(short8*)(bt + n * BST + h * 8) = v;
    }
}

// gather 64-edge tile: fp32 x rows -> bf16 LDS tiles + psi(norm), psi(dot), eattr -> ext
__device__ __forceinline__ void gather_tile(const float* __restrict__ x,
                                            const int* __restrict__ ridx,
                                            const int* __restrict__ cidx,
                                            const float* __restrict__ eattr,
                                            int e0, int t,
                                            short* lxi, short* lxj, short* lext) {
    const int le = t >> 2, q = t & 3;
    const int r = ridx[le], c = cidx[le];
    const float4* xr4 = (const float4*)(x + (size_t)r * NF) + q * 8;
    const float4* xc4 = (const float4*)(x + (size_t)c * NF) + q * 8;
    float nrm = 0.f, dot = 0.f, a00 = 0.f, b00 = 0.f;
    #pragma unroll
    for (int u = 0; u < 4; ++u) {
        float4 a0 = xr4[2*u], a1 = xr4[2*u+1];
        float4 b0 = xc4[2*u], b1 = xc4[2*u+1];
        if (u == 0) { a00 = a0.x; b00 = b0.x; }
        float d;
        d = a0.x-b0.x; nrm -= d*d; dot -= a0.x*b0.x;
        d = a0.y-b0.y; nrm -= d*d; dot -= a0.y*b0.y;
        d = a0.z-b0.z; nrm -= d*d; dot -= a0.z*b0.z;
        d = a0.w-b0.w; nrm -= d*d; dot -= a0.w*b0.w;
        d = a1.x-b1.x; nrm -= d*d; dot -= a1.x*b1.x;
        d = a1.y-b1.y; nrm -= d*d; dot -= a1.y*b1.y;
        d = a1.z-b1.z; nrm -= d*d; dot -= a1.z*b1.z;
        d = a1.w-b1.w; nrm -= d*d; dot -= a1.w*b1.w;
        short8 sa, sb;
        sa[0]=f2bf(a0.x); sa[1]=f2bf(a0.y); sa[2]=f2bf(a0.z); sa[3]=f2bf(a0.w);
        sa[4]=f2bf(a1.x); sa[5]=f2bf(a1.y); sa[6]=f2bf(a1.z); sa[7]=f2bf(a1.w);
        sb[0]=f2bf(b0.x); sb[1]=f2bf(b0.y); sb[2]=f2bf(b0.z); sb[3]=f2bf(b0.w);
        sb[4]=f2bf(b1.x); sb[5]=f2bf(b1.y); sb[6]=f2bf(b1.z); sb[7]=f2bf(b1.w);
        *(short8*)(lxi + le * XST + q * 32 + u * 8) = sa;
        *(short8*)(lxj + le * XST + q * 32 + u * 8) = sb;
    }
    if (q == 0) {  // metric fix: component 0 carries +, not -
        float d0 = a00 - b00;
        nrm += 2.f * d0 * d0;
        dot += 2.f * a00 * b00;
    }
    nrm += __shfl_xor(nrm, 1); nrm += __shfl_xor(nrm, 2);
    dot += __shfl_xor(dot, 1); dot += __shfl_xor(dot, 2);
    if (q == 0) {
        float4 ea = ((const float4*)eattr)[e0 + le];
        short8 ev;
        ev[0]=f2bf(ea.x); ev[1]=f2bf(ea.y); ev[2]=f2bf(ea.z); ev[3]=f2bf(ea.w);
        ev[4]=f2bf(psif(nrm)); ev[5]=f2bf(psif(dot)); ev[6]=0; ev[7]=0;
        *(short8*)(lext + le * 32) = ev;
    } else {
        short8 ez = {0,0,0,0,0,0,0,0};
        *(short8*)(lext + le * 32 + q * 8) = ez;
    }
}

// ---------------------------------------------------------------------------
// Pass 1: MFMA GEMM0 -> per-channel sum/sumsq (register accumulation)
// ---------------------------------------------------------------------------
__global__ __launch_bounds__(NT, 3)
void stats_pass(const float* __restrict__ x,
                const int* __restrict__ ei,
                const float* __restrict__ eattr,
                const unsigned short* __restrict__ wt1,
                float* __restrict__ gstats)
{
    __shared__ short lxi[TE * XST];
    __shared__ short lxj[TE * XST];
    __shared__ short lext[TE * 32];
    __shared__ short lbt[128 * BST];
    __shared__ int ridx[TE], cidx[TE];

    const int t = threadIdx.x;
    const int lane = t & 63, quad = lane >> 4, ln15 = lane & 15;
    const int wv = t >> 6, we = wv >> 1, wc = wv & 1;

    float ss[4] = {0.f,0.f,0.f,0.f}, sq[4] = {0.f,0.f,0.f,0.f};

    for (int tile = blockIdx.x; tile < NTILES; tile += gridDim.x) {
        const int e0 = tile * TE;
        __syncthreads();
        if (t < TE) ridx[t] = ei[e0 + t];
        else if (t < 2 * TE) cidx[t - TE] = ei[NE + e0 + (t - TE)];
        __syncthreads();
        gather_tile(x, ridx, cidx, eattr, e0, t, lxi, lxj, lext);

        float4v acc[2][4];
        #pragma unroll
        for (int a = 0; a < 2; ++a)
            #pragma unroll
            for (int b = 0; b < 4; ++b) { float4v z = {0.f,0.f,0.f,0.f}; acc[a][b] = z; }

        for (int ks = 0; ks < 9; ++ks) {
            __syncthreads();
            stage_b(wt1, K1P, ks, lbt, t);
            __syncthreads();
            const short* asrc; int ak, astr;
            if (ks < 4)      { asrc = lxi;  ak = ks * 32;       astr = XST; }
            else if (ks < 8) { asrc = lxj;  ak = (ks - 4) * 32; astr = XST; }
            else             { asrc = lext; ak = 0;             astr = 32;  }
            short8 af[2], bfr[4];
            #pragma unroll
            for (int ef = 0; ef < 2; ++ef)
                af[ef] = *(const short8*)(asrc + (we*32 + ef*16 + ln15) * astr + ak + quad*8);
            #pragma unroll
            for (int fc = 0; fc < 4; ++fc)
                bfr[fc] = *(const short8*)(lbt + (wc*64 + fc*16 + ln15) * BST + quad*8);
            #pragma unroll
            for (int ef = 0; ef < 2; ++ef)
                #pragma unroll
                for (int fc = 0; fc < 4; ++fc)
                    acc[ef][fc] = __builtin_amdgcn_mfma_f32_16x16x32_bf16(af[ef], bfr[fc], acc[ef][fc], 0, 0, 0);
        }
        #pragma unroll
        for (int fc = 0; fc < 4; ++fc)
            #pragma unroll
            for (int ef = 0; ef < 2; ++ef)
                #pragma unroll
                for (int rg = 0; rg < 4; ++rg) {
                    float v = acc[ef][fc][rg];
                    ss[fc] += v;
                    sq[fc] = fmaf(v, v, sq[fc]);
                }
    }
    #pragma unroll
    for (int fc = 0; fc < 4; ++fc) {
        ss[fc] += __shfl_xor(ss[fc], 16); ss[fc] += __shfl_xor(ss[fc], 32);
        sq[fc] += __shfl_xor(sq[fc], 16); sq[fc] += __shfl_xor(sq[fc], 32);
    }
    if (lane < 16) {
        #pragma unroll
        for (int fc = 0; fc < 4; ++fc) {
            int c = wc * 64 + fc * 16 + lane;
            atomicAdd(&gstats[c], ss[fc]);
            atomicAdd(&gstats[128 + c], sq[fc]);
        }
    }
}

// ---------------------------------------------------------------------------
__global__ void bn_finalize(const float* __restrict__ gstats,
                            const float* __restrict__ gamma,
                            const float* __restrict__ beta,
                            float* __restrict__ scsh)
{
    int c = threadIdx.x;
    float mu  = gstats[c] * (1.f / NE);
    float var = gstats[128 + c] * (1.f / NE) - mu * mu;
    var = fmaxf(var, 0.f);
    float inv = rsqrtf(var + EPS);
    float scale = gamma[c] * inv;
    scsh[c]       = scale;
    scsh[128 + c] = beta[c] - mu * scale;
}

// ---------------------------------------------------------------------------
// Pass 2: GEMM0->BN->ReLU->GEMM1->gate->GEMM2->Wb dot -> write s_e (NO scatter)
// ---------------------------------------------------------------------------
__global__ __launch_bounds__(NT, 3)
void edge_pass(const float* __restrict__ x,
               const int* __restrict__ ei,
               const float* __restrict__ eattr,
               const unsigned short* __restrict__ wt1,
               const float* __restrict__ scsh,
               const unsigned short* __restrict__ wt2,
               const float* __restrict__ b2,
               const unsigned short* __restrict__ wta,
               const float* __restrict__ ba,
               const float* __restrict__ wb,
               const float* __restrict__ wm,
               const float* __restrict__ bm,
               float* __restrict__ sG)
{
    __shared__ short lxi[TE * XST];
    __shared__ short lxj[TE * XST];
    __shared__ short lext[TE * 32];
    __shared__ short lbt[128 * BST];
    __shared__ int ridx[TE], cidx[TE];
    __shared__ float gpart[2][TE];
    __shared__ float spart[2][TE];
    __shared__ float wgt[TE];

    const int t = threadIdx.x;
    const int lane = t & 63, quad = lane >> 4, ln15 = lane & 15;
    const int wv = t >> 6, we = wv >> 1, wc = wv & 1;
    const int e0 = blockIdx.x * TE;
    const float bmv = bm[0];

    if (t < TE) ridx[t] = ei[e0 + t];
    else if (t < 2 * TE) cidx[t - TE] = ei[NE + e0 + (t - TE)];
    __syncthreads();
    gather_tile(x, ridx, cidx, eattr, e0, t, lxi, lxj, lext);

    float4v acc[2][4];
    #pragma unroll
    for (int a = 0; a < 2; ++a)
        #pragma unroll
        for (int b = 0; b < 4; ++b) { float4v z = {0.f,0.f,0.f,0.f}; acc[a][b] = z; }

    // ---- GEMM0: hpre = m @ W1 ----
    for (int ks = 0; ks < 9; ++ks) {
        __syncthreads();
        stage_b(wt1, K1P, ks, lbt, t);
        __syncthreads();
        const short* asrc; int ak, astr;
        if (ks < 4)      { asrc = lxi;  ak = ks * 32;       astr = XST; }
        else if (ks < 8) { asrc = lxj;  ak = (ks - 4) * 32; astr = XST; }
        else             { asrc = lext; ak = 0;             astr = 32;  }
        short8 af[2], bfr[4];
        #pragma unroll
        for (int ef = 0; ef < 2; ++ef)
            af[ef] = *(const short8*)(asrc + (we*32 + ef*16 + ln15) * astr + ak + quad*8);
        #pragma unroll
        for (int fc = 0; fc < 4; ++fc)
            bfr[fc] = *(const short8*)(lbt + (wc*64 + fc*16 + ln15) * BST + quad*8);
        #pragma unroll
        for (int ef = 0; ef < 2; ++ef)
            #pragma unroll
            for (int fc = 0; fc < 4; ++fc)
                acc[ef][fc] = __builtin_amdgcn_mfma_f32_16x16x32_bf16(af[ef], bfr[fc], acc[ef][fc], 0, 0, 0);
    }

    // epilogue0: BN + ReLU -> hid (bf16) into lxi
    #pragma unroll
    for (int fc = 0; fc < 4; ++fc) {
        int c = wc * 64 + fc * 16 + ln15;
        float sc = scsh[c], sf = scsh[128 + c];
        #pragma unroll
        for (int ef = 0; ef < 2; ++ef)
            #pragma unroll
            for (int rg = 0; rg < 4; ++rg) {
                int r = we * 32 + ef * 16 + quad * 4 + rg;
                float v = fmaxf(fmaf(acc[ef][fc][rg], sc, sf), 0.f);
                lxi[r * XST + c] = f2bf(v);
            }
    }

    // ---- GEMM1: mij_raw = relu(hid @ W2 + b2) ----
    #pragma unroll
    for (int a = 0; a < 2; ++a)
        #pragma unroll
        for (int b = 0; b < 4; ++b) { float4v z = {0.f,0.f,0.f,0.f}; acc[a][b] = z; }
    for (int ks = 0; ks < 4; ++ks) {
        __syncthreads();
        stage_b(wt2, NF, ks, lbt, t);
        __syncthreads();
        short8 af[2], bfr[4];
        #pragma unroll
        for (int ef = 0; ef < 2; ++ef)
            af[ef] = *(const short8*)(lxi + (we*32 + ef*16 + ln15) * XST + ks*32 + quad*8);
        #pragma unroll
        for (int fc = 0; fc < 4; ++fc)
            bfr[fc] = *(const short8*)(lbt + (wc*64 + fc*16 + ln15) * BST + quad*8);
        #pragma unroll
        for (int ef = 0; ef < 2; ++ef)
            #pragma unroll
            for (int fc = 0; fc < 4; ++fc)
                acc[ef][fc] = __builtin_amdgcn_mfma_f32_16x16x32_bf16(af[ef], bfr[fc], acc[ef][fc], 0, 0, 0);
    }

    // epilogue1: +b2, ReLU -> mij (bf16) into lxj; gate partial dots with Wm
    {
        float p[2][4] = {{0.f,0.f,0.f,0.f},{0.f,0.f,0.f,0.f}};
        #pragma unroll
        for (int fc = 0; fc < 4; ++fc) {
            int c = wc * 64 + fc * 16 + ln15;
            float bb = b2[c], wmv = wm[c];
            #pragma unroll
            for (int ef = 0; ef < 2; ++ef)
                #pragma unroll
                for (int rg = 0; rg < 4; ++rg) {
                    int r = we * 32 + ef * 16 + quad * 4 + rg;
                    float v = fmaxf(acc[ef][fc][rg] + bb, 0.f);
                    lxj[r * XST + c] = f2bf(v);
                    p[ef][rg] = fmaf(v, wmv, p[ef][rg]);
                }
        }
        #pragma unroll
        for (int ef = 0; ef < 2; ++ef)
            #pragma unroll
            for (int rg = 0; rg < 4; ++rg) {
                p[ef][rg] += __shfl_xor(p[ef][rg], 1);
                p[ef][rg] += __shfl_xor(p[ef][rg], 2);
                p[ef][rg] += __shfl_xor(p[ef][rg], 4);
                p[ef][rg] += __shfl_xor(p[ef][rg], 8);
            }
        if (ln15 == 0) {
            #pragma unroll
            for (int ef = 0; ef < 2; ++ef)
                #pragma unroll
                for (int rg = 0; rg < 4; ++rg)
                    gpart[wc][we * 32 + ef * 16 + quad * 4 + rg] = p[ef][rg];
        }
    }
    __syncthreads();
    if (t < TE) wgt[t] = sigm(gpart[0][t] + gpart[1][t] + bmv);

    // ---- GEMM2: relu(w * (mij_raw @ Wa) + ba) . Wb ----
    #pragma unroll
    for (int a = 0; a < 2; ++a)
        #pragma unroll
        for (int b = 0; b < 4; ++b) { float4v z = {0.f,0.f,0.f,0.f}; acc[a][b] = z; }
    for (int ks = 0; ks < 4; ++ks) {
        __syncthreads();
        stage_b(wta, NF, ks, lbt, t);
        __syncthreads();
        short8 af[2], bfr[4];
        #pragma unroll
        for (int ef = 0; ef < 2; ++ef)
            af[ef] = *(const short8*)(lxj + (we*32 + ef*16 + ln15) * XST + ks*32 + quad*8);
        #pragma unroll
        for (int fc = 0; fc < 4; ++fc)
            bfr[fc] = *(const short8*)(lbt + (wc*64 + fc*16 + ln15) * BST + quad*8);
        #pragma unroll
        for (int ef = 0; ef < 2; ++ef)
            #pragma unroll
            for (int fc = 0; fc < 4; ++fc)
                acc[ef][fc] = __builtin_amdgcn_mfma_f32_16x16x32_bf16(af[ef], bfr[fc], acc[ef][fc], 0, 0, 0);
    }
    {
        float p[2][4] = {{0.f,0.f,0.f,0.f},{0.f,0.f,0.f,0.f}};
        #pragma unroll
        for (int fc = 0; fc < 4; ++fc) {
            int c = wc * 64 + fc * 16 + ln15;
            float bav = ba[c], wbv = wb[c];
            #pragma unroll
            for (int ef = 0; ef < 2; ++ef)
                #pragma unroll
                for (int rg = 0; rg < 4; ++rg) {
                    int r = we * 32 + ef * 16 + quad * 4 + rg;
                    float v = fmaxf(fmaf(wgt[r], acc[ef][fc][rg], bav), 0.f);
                    p[ef][rg] = fmaf(v, wbv, p[ef][rg]);
                }
        }
        #pragma unroll
        for (int ef = 0; ef < 2; ++ef)
            #pragma unroll
            for (int rg = 0; rg < 4; ++rg) {
                p[ef][rg] += __shfl_xor(p[ef][rg], 1);
                p[ef][rg] += __shfl_xor(p[ef][rg], 2);
                p[ef][rg] += __shfl_xor(p[ef][rg], 4);
                p[ef][rg] += __shfl_xor(p[ef][rg], 8);
            }
        if (ln15 == 0) {
            #pragma unroll
            for (int ef = 0; ef < 2; ++ef)
                #pragma unroll
                for (int rg = 0; rg < 4; ++rg)
                    spart[wc][we * 32 + ef * 16 + quad * 4 + rg] = p[ef][rg];
        }
    }
    __syncthreads();
    if (t < TE) sG[e0 + t] = spart[0][t] + spart[1][t];   // coalesced, no atomics
}

// ---------------------------------------------------------------------------
// CSR build: histogram -> 1-block scan -> fill
// ---------------------------------------------------------------------------
__global__ __launch_bounds__(NT)
void hist_k(const int* __restrict__ ei, int* __restrict__ deg)
{
    int e = blockIdx.x * NT + threadIdx.x;
    if (e < NE) atomicAdd(&deg[ei[e]], 1);
}

__global__ __launch_bounds__(NT)
void scan_k(const int* __restrict__ deg, int* __restrict__ rowstart,
            int* __restrict__ cursor)
{
    __shared__ int part[NT];
    const int t = threadIdx.x;
    const int CH = (NND + NT - 1) / NT;   // 79
    const int base = t * CH;
    int sum = 0;
    for (int i = 0; i < CH; ++i) {
        int idx = base + i;
        if (idx < NND) sum += deg[idx];
    }
    part[t] = sum;
    __syncthreads();
    int pre = 0;
    for (int j = 0; j < t; ++j) pre += part[j];   // one-time 20k scan, fine
    int run = pre;
    for (int i = 0; i < CH; ++i) {
        int idx = base + i;
        if (idx < NND) {
            rowstart[idx] = run;
            cursor[idx]   = run;
            run += deg[idx];
        }
    }
    if (t == NT - 1) rowstart[NND] = run;
}

__global__ __launch_bounds__(NT)
void fill_k(const int* __restrict__ ei, int* __restrict__ cursor,
            int* __restrict__ csr)
{
    int e = blockIdx.x * NT + threadIdx.x;
    if (e < NE) {
        int pos = atomicAdd(&cursor[ei[e]], 1);
        csr[pos] = e;
    }
}

// ---------------------------------------------------------------------------
// Aggregation: one wave per node, gather-based, zero atomics.
// xn[r] = x[r] + sum_e clip((x[r]-x[col_e]) * s_e)
// ---------------------------------------------------------------------------
__global__ __launch_bounds__(NT)
void aggregate_k(const float* __restrict__ x,
                 const float* __restrict__ sG,
                 const int* __restrict__ csr,
                 const int* __restrict__ rowstart,
                 const int* __restrict__ colidx,
                 float* __restrict__ xn)
{
    const int w  = (blockIdx.x * NT + threadIdx.x) >> 6;
    const int ln = threadIdx.x & 63;
    if (w >= NND) return;
    const int beg = rowstart[w], end = rowstart[w + 1];
    const float* xr = x + (size_t)w * NF;
    const float xr0 = xr[ln], xr1 = xr[ln + 64];
    float a0 = 0.f, a1 = 0.f;
    for (int i = beg; i < end; ++i) {
        int e = csr[i];
        int c = colidx[e];
        float s = sG[e];
        const float* xc = x + (size_t)c * NF;
        a0 += clipf((xr0 - xc[ln])      * s);
        a1 += clipf((xr1 - xc[ln + 64]) * s);
    }
    xn[(size_t)w * NF + ln]      = xr0 + a0;
    xn[(size_t)w * NF + ln + 64] = xr1 + a1;
}

// ---------------------------------------------------------------------------
__global__ __launch_bounds__(NT)
void prep_w1(const float* __restrict__ W1, unsigned short* __restrict__ wt1)
{
    int i = blockIdx.x * NT + threadIdx.x;
    if (i >= 3 * 128 * K1P) return;
    int l = i / (128 * K1P);
    int r = i % (128 * K1P);
    int n = r / K1P, k = r % K1P;
    float v = (k < 262) ? W1[((size_t)l * 262 + k) * 128 + n] : 0.f;
    wt1[i] = (unsigned short)f2bf(v);
}

__global__ __launch_bounds__(NT)
void prep_w128(const float* __restrict__ W, unsigned short* __restrict__ wt)
{
    int i = blockIdx.x * NT + threadIdx.x;
    if (i >= 3 * 128 * 128) return;
    int l = i / (128 * 128);
    int r = i % (128 * 128);
    int n = r / 128, k = r % 128;
    wt[i] = (unsigned short)f2bf(W[((size_t)l * 128 + k) * 128 + n]);
}

__global__ __launch_bounds__(NT)
void finalk(const float* __restrict__ x, const float* __restrict__ We,
            const float* __restrict__ be, float* __restrict__ out)
{
    int gw = (blockIdx.x * NT + threadIdx.x) >> 6;
    int ln = threadIdx.x & 63;
    if (gw >= NND) return;
    const float* xr = x + (size_t)gw * NF;
    float a0 = xr[ln], a1 = xr[ln + 64];
    float o0 = a0 * We[ln * 2]     + a1 * We[(ln + 64) * 2];
    float o1 = a0 * We[ln * 2 + 1] + a1 * We[(ln + 64) * 2 + 1];
    #pragma unroll
    for (int m = 1; m < 64; m <<= 1) { o0 += __shfl_xor(o0, m); o1 += __shfl_xor(o1, m); }
    if (ln == 0) {
        out[gw * 2]     = sigm(o0 + be[0]);
        out[gw * 2 + 1] = sigm(o1 + be[1]);
    }
}

// ---------------------------------------------------------------------------
extern "C" void kernel_launch(void* const* d_in, const int* in_sizes, int n_in,
                              void* d_out, int out_size, void* d_ws, size_t ws_size,
                              hipStream_t stream) {
    const float* x   = (const float*)d_in[0];
    const int*   ei  = (const int*)d_in[1];
    const float* ea  = (const float*)d_in[2];
    const float* W1  = (const float*)d_in[3];
    const float* ga  = (const float*)d_in[4];
    const float* bet = (const float*)d_in[5];
    const float* W2  = (const float*)d_in[6];
    const float* b2  = (const float*)d_in[7];
    const float* Wa  = (const float*)d_in[8];
    const float* ba  = (const float*)d_in[9];
    const float* Wb  = (const float*)d_in[10];
    const float* Wm  = (const float*)d_in[11];
    const float* bm  = (const float*)d_in[12];
    const float* We  = (const float*)d_in[13];
    const float* be  = (const float*)d_in[14];
    float* out = (float*)d_out;

    float* ws     = (float*)d_ws;
    float* gstats = ws;                              // 256 f
    float* scsh   = ws + 256;                        // 256 f
    int*   deg      = (int*)(ws + 512);              // NND
    int*   rowstart = deg + NND;                     // NND+1
    int*   cursor   = rowstart + NND + 1;            // NND
    int*   csr      = cursor + NND;                  // NE
    float* sG       = (float*)(csr + NE);            // NE
    float* xA       = sG + NE;
    float* xB       = xA + (size_t)NND * NF;
    unsigned short* wt1 = (unsigned short*)(xB + (size_t)NND * NF);
    unsigned short* wt2 = wt1 + (size_t)3 * 128 * K1P;
    unsigned short* wta = wt2 + (size_t)3 * 128 * 128;

    prep_w1  <<<(3 * 128 * K1P + NT - 1) / NT, NT, 0, stream>>>(W1, wt1);
    prep_w128<<<(3 * 128 * 128 + NT - 1) / NT, NT, 0, stream>>>(W2, wt2);
    prep_w128<<<(3 * 128 * 128 + NT - 1) / NT, NT, 0, stream>>>(Wa, wta);

    // CSR build (edge_index constant across layers)
    hipMemsetAsync(deg, 0, NND * sizeof(int), stream);
    hist_k<<<(NE + NT - 1) / NT, NT, 0, stream>>>(ei, deg);
    scan_k<<<1, NT, 0, stream>>>(deg, rowstart, cursor);
    fill_k<<<(NE + NT - 1) / NT, NT, 0, stream>>>(ei, cursor, csr);

    const float* xc = x;
    float* buf[2] = { xA, xB };

    for (int l = 0; l < 3; ++l) {
        float* xn = buf[l & 1];
        hipMemsetAsync(gstats, 0, 256 * sizeof(float), stream);
        stats_pass<<<1024, NT, 0, stream>>>(xc, ei, ea, wt1 + (size_t)l * 128 * K1P, gstats);
        bn_finalize<<<1, 128, 0, stream>>>(gstats, ga + l * NF, bet + l * NF, scsh);
        edge_pass<<<NTILES, NT, 0, stream>>>(xc, ei, ea,
                                             wt1 + (size_t)l * 128 * K1P, scsh,
                                             wt2 + (size_t)l * 128 * 128, b2 + l * NF,
                                             wta + (size_t)l * 128 * 128, ba + l * NF,
                                             Wb + l * NF, Wm + l * NF, bm + l, sG);
        aggregate_k<<<(NND * 64 + NT - 1) / NT, NT, 0, stream>>>(xc, sG, csr, rowstart,
                                                                 ei + NE, xn);
        xc = xn;
    }
    finalk<<<(NND * 64 + NT - 1) / NT, NT, 0, stream>>>(xc, We, be, out);
}